// Round 1
// baseline (87.191 us; speedup 1.0000x reference)
//
#include <hip/hip_runtime.h>

#define T_STEPS 128   // timesteps (4 x 32-bit mask words)

// ---------------------------------------------------------------------------
// Kernel 1: CSR row pointers from sorted row indices via binary search.
// One thread per row in [0, n_rows]; start[r] = lower_bound(rows, r).
// ---------------------------------------------------------------------------
__global__ __launch_bounds__(256) void build_row_ptr_kernel(
    const int* __restrict__ rows, int nnz, int n_rows, int* __restrict__ start)
{
    int r = blockIdx.x * 256 + threadIdx.x;
    if (r > n_rows) return;
    int lo = 0, hi = nnz;
    while (lo < hi) {
        int mid = (lo + hi) >> 1;
        if (rows[mid] < r) lo = mid + 1; else hi = mid;
    }
    start[r] = lo;
}

// ---------------------------------------------------------------------------
// Kernel 2: compress binary spike matrix (T=128, C) into 4 bit-plane words
// per column: mask[q*C + c] bit t2 = (spikes[(q*32+t2)*C + c] != 0).
// Loads are coalesced across c (consecutive lanes, fixed t).
// ---------------------------------------------------------------------------
__global__ __launch_bounds__(256) void build_masks_kernel(
    const float* __restrict__ spikes, int C, unsigned int* __restrict__ mask)
{
    int c = blockIdx.x * 256 + threadIdx.x;
    if (c >= C) return;
    unsigned int m0 = 0u, m1 = 0u, m2 = 0u, m3 = 0u;
    #pragma unroll 4
    for (int t = 0; t < 32; ++t) {
        if (spikes[(size_t)(t)       * C + c] != 0.0f) m0 |= (1u << t);
        if (spikes[(size_t)(t +  32) * C + c] != 0.0f) m1 |= (1u << t);
        if (spikes[(size_t)(t +  64) * C + c] != 0.0f) m2 |= (1u << t);
        if (spikes[(size_t)(t +  96) * C + c] != 0.0f) m3 |= (1u << t);
    }
    mask[(size_t)0 * C + c] = m0;
    mask[(size_t)1 * C + c] = m1;
    mask[(size_t)2 * C + c] = m2;
    mask[(size_t)3 * C + c] = m3;
}

// ---------------------------------------------------------------------------
// Kernel 3 (main): one thread per (row r, t-quarter q). Accumulate both
// sparse inputs via bitmask + conditional add; single coalesced write pass.
// ---------------------------------------------------------------------------
__global__ __launch_bounds__(256) void sparse_main_kernel(
    const int* __restrict__ lgn_cols, const float* __restrict__ lgn_w,
    const int* __restrict__ lgn_start,
    const int* __restrict__ bkg_cols, const float* __restrict__ bkg_w,
    const int* __restrict__ bkg_start,
    const unsigned int* __restrict__ lgn_mask,  // [4][lgn_C]
    const unsigned int* __restrict__ bkg_mask,  // [4][bkg_C]
    int lgn_C, int bkg_C, int R,
    float* __restrict__ out)
{
    int r = blockIdx.x * 256 + threadIdx.x;
    int q = blockIdx.y;           // which 32-step quarter of T
    if (r >= R) return;

    float acc[32];
    #pragma unroll
    for (int t = 0; t < 32; ++t) acc[t] = 0.0f;

    // LGN contributions
    {
        const unsigned int* lm = lgn_mask + (size_t)q * lgn_C;
        int i0 = lgn_start[r], i1 = lgn_start[r + 1];
        for (int i = i0; i < i1; ++i) {
            float wt = lgn_w[i];
            unsigned int m = lm[lgn_cols[i]];
            #pragma unroll
            for (int t = 0; t < 32; ++t)
                acc[t] += ((m >> t) & 1u) ? wt : 0.0f;
        }
    }
    // BKG contributions
    {
        const unsigned int* bm = bkg_mask + (size_t)q * bkg_C;
        int i0 = bkg_start[r], i1 = bkg_start[r + 1];
        for (int i = i0; i < i1; ++i) {
            float wt = bkg_w[i];
            unsigned int m = bm[bkg_cols[i]];
            #pragma unroll
            for (int t = 0; t < 32; ++t)
                acc[t] += ((m >> t) & 1u) ? wt : 0.0f;
        }
    }

    float* op = out + (size_t)(q * 32) * R + r;
    #pragma unroll
    for (int t = 0; t < 32; ++t) op[(size_t)t * R] = acc[t];
}

// ---------------------------------------------------------------------------
// Fallback (small ws): inline binary search + direct float gathers.
// ---------------------------------------------------------------------------
__global__ __launch_bounds__(256) void sparse_fallback_kernel(
    const int* __restrict__ lgn_rows, const int* __restrict__ lgn_cols,
    const float* __restrict__ lgn_w, int nnz_l,
    const int* __restrict__ bkg_rows, const int* __restrict__ bkg_cols,
    const float* __restrict__ bkg_w, int nnz_b,
    const float* __restrict__ lgn_spikes, const float* __restrict__ bkg_spikes,
    int lgn_C, int bkg_C, int R,
    float* __restrict__ out)
{
    int r = blockIdx.x * 256 + threadIdx.x;
    int q = blockIdx.y;
    if (r >= R) return;

    float acc[32];
    #pragma unroll
    for (int t = 0; t < 32; ++t) acc[t] = 0.0f;

    {
        int lo = 0, hi = nnz_l;
        while (lo < hi) { int mid = (lo + hi) >> 1; if (lgn_rows[mid] < r) lo = mid + 1; else hi = mid; }
        for (int i = lo; i < nnz_l && lgn_rows[i] == r; ++i) {
            float wt = lgn_w[i];
            const float* sp = lgn_spikes + (size_t)(q * 32) * lgn_C + lgn_cols[i];
            #pragma unroll
            for (int t = 0; t < 32; ++t)
                acc[t] = fmaf(wt, sp[(size_t)t * lgn_C], acc[t]);
        }
    }
    {
        int lo = 0, hi = nnz_b;
        while (lo < hi) { int mid = (lo + hi) >> 1; if (bkg_rows[mid] < r) lo = mid + 1; else hi = mid; }
        for (int i = lo; i < nnz_b && bkg_rows[i] == r; ++i) {
            float wt = bkg_w[i];
            const float* sp = bkg_spikes + (size_t)(q * 32) * bkg_C + bkg_cols[i];
            #pragma unroll
            for (int t = 0; t < 32; ++t)
                acc[t] = fmaf(wt, sp[(size_t)t * bkg_C], acc[t]);
        }
    }

    float* op = out + (size_t)(q * 32) * R + r;
    #pragma unroll
    for (int t = 0; t < 32; ++t) op[(size_t)t * R] = acc[t];
}

extern "C" void kernel_launch(void* const* d_in, const int* in_sizes, int n_in,
                              void* d_out, int out_size, void* d_ws, size_t ws_size,
                              hipStream_t stream)
{
    const float* lgn_spikes = (const float*)d_in[0];
    const float* bkg_spikes = (const float*)d_in[1];
    const int*   lgn_rows   = (const int*)d_in[2];
    const int*   lgn_cols   = (const int*)d_in[3];
    const float* lgn_w      = (const float*)d_in[4];
    const int*   bkg_rows   = (const int*)d_in[5];
    const int*   bkg_cols   = (const int*)d_in[6];
    const float* bkg_w      = (const float*)d_in[7];
    float* out = (float*)d_out;

    const int nnz_l = in_sizes[2];
    const int nnz_b = in_sizes[5];
    const int lgn_C = in_sizes[0] / T_STEPS;   // 17400
    const int bkg_C = in_sizes[1] / T_STEPS;   // 100
    const int R     = out_size / T_STEPS;      // 200000

    // ws layout (16B-aligned sections)
    size_t off = 0;
    auto take = [&](size_t bytes) { size_t o = off; off = (off + bytes + 15) & ~(size_t)15; return o; };
    size_t o_lgn_start = take((size_t)(R + 1) * sizeof(int));
    size_t o_bkg_start = take((size_t)(R + 1) * sizeof(int));
    size_t o_lgn_mask  = take((size_t)4 * lgn_C * sizeof(unsigned int));
    size_t o_bkg_mask  = take((size_t)4 * bkg_C * sizeof(unsigned int));
    size_t need = off;

    dim3 blk(256);
    dim3 grid_main((R + 255) / 256, 4);

    if (ws_size >= need) {
        char* ws = (char*)d_ws;
        int* lgn_start = (int*)(ws + o_lgn_start);
        int* bkg_start = (int*)(ws + o_bkg_start);
        unsigned int* lgn_mask = (unsigned int*)(ws + o_lgn_mask);
        unsigned int* bkg_mask = (unsigned int*)(ws + o_bkg_mask);

        build_row_ptr_kernel<<<(R + 1 + 255) / 256, blk, 0, stream>>>(lgn_rows, nnz_l, R, lgn_start);
        build_row_ptr_kernel<<<(R + 1 + 255) / 256, blk, 0, stream>>>(bkg_rows, nnz_b, R, bkg_start);
        build_masks_kernel<<<(lgn_C + 255) / 256, blk, 0, stream>>>(lgn_spikes, lgn_C, lgn_mask);
        build_masks_kernel<<<(bkg_C + 255) / 256, blk, 0, stream>>>(bkg_spikes, bkg_C, bkg_mask);

        sparse_main_kernel<<<grid_main, blk, 0, stream>>>(
            lgn_cols, lgn_w, lgn_start,
            bkg_cols, bkg_w, bkg_start,
            lgn_mask, bkg_mask,
            lgn_C, bkg_C, R, out);
    } else {
        sparse_fallback_kernel<<<grid_main, blk, 0, stream>>>(
            lgn_rows, lgn_cols, lgn_w, nnz_l,
            bkg_rows, bkg_cols, bkg_w, nnz_b,
            lgn_spikes, bkg_spikes,
            lgn_C, bkg_C, R, out);
    }
}

// Round 2
// 86.693 us; speedup vs baseline: 1.0058x; 1.0058x over previous
//
#include <hip/hip_runtime.h>

#define T_STEPS 128   // timesteps (4 x 32-bit mask words)

// ---------------------------------------------------------------------------
// Kernel 1: CSR row pointers for BOTH sparse inputs (blockIdx.y selects).
// start[r] = lower_bound(rows, r) for r in [0, n_rows].
// ---------------------------------------------------------------------------
__global__ __launch_bounds__(256) void build_row_ptr2_kernel(
    const int* __restrict__ lgn_rows, int nnz_l, int* __restrict__ lgn_start,
    const int* __restrict__ bkg_rows, int nnz_b, int* __restrict__ bkg_start,
    int n_rows)
{
    int r = blockIdx.x * 256 + threadIdx.x;
    if (r > n_rows) return;
    const int* rows;
    int nnz;
    int* start;
    if (blockIdx.y == 0) { rows = lgn_rows; nnz = nnz_l; start = lgn_start; }
    else                 { rows = bkg_rows; nnz = nnz_b; start = bkg_start; }
    int lo = 0, hi = nnz;
    while (lo < hi) {
        int mid = (lo + hi) >> 1;
        if (rows[mid] < r) lo = mid + 1; else hi = mid;
    }
    start[r] = lo;
}

// ---------------------------------------------------------------------------
// Kernel 2: compress both binary spike matrices (T=128, C) into uint4 per
// column (bit t of word q = spike at t = q*32 + bit). Column-major uint4
// layout so the main kernel fetches all 128 timesteps in ONE 16B gather.
// ---------------------------------------------------------------------------
__global__ __launch_bounds__(256) void build_masks2_kernel(
    const float* __restrict__ lgn_spikes, int lgn_C, uint4* __restrict__ lgn_mask,
    const float* __restrict__ bkg_spikes, int bkg_C, uint4* __restrict__ bkg_mask)
{
    int c = blockIdx.x * 256 + threadIdx.x;
    const float* sp;
    uint4* mask;
    int C, cc;
    if (c < lgn_C)              { sp = lgn_spikes; mask = lgn_mask; C = lgn_C; cc = c; }
    else if (c < lgn_C + bkg_C) { sp = bkg_spikes; mask = bkg_mask; C = bkg_C; cc = c - lgn_C; }
    else return;

    unsigned int m0 = 0u, m1 = 0u, m2 = 0u, m3 = 0u;
    #pragma unroll 4
    for (int t = 0; t < 32; ++t) {
        if (sp[(size_t)(t)       * C + cc] != 0.0f) m0 |= (1u << t);
        if (sp[(size_t)(t +  32) * C + cc] != 0.0f) m1 |= (1u << t);
        if (sp[(size_t)(t +  64) * C + cc] != 0.0f) m2 |= (1u << t);
        if (sp[(size_t)(t +  96) * C + cc] != 0.0f) m3 |= (1u << t);
    }
    mask[cc] = make_uint4(m0, m1, m2, m3);
}

// ---------------------------------------------------------------------------
// Kernel 3 (main): one thread per row r, ALL 128 timesteps in registers.
// Each synapse: 1 col load + 1 weight load + 1 uint4 mask gather, then
// 128 x (bfe_i32 + and + add) conditional accumulate. Single coalesced
// write pass (lanes r-consecutive per t).
// ---------------------------------------------------------------------------
__global__ __launch_bounds__(256) void sparse_main_kernel(
    const int* __restrict__ lgn_cols, const float* __restrict__ lgn_w,
    const int* __restrict__ lgn_start,
    const int* __restrict__ bkg_cols, const float* __restrict__ bkg_w,
    const int* __restrict__ bkg_start,
    const uint4* __restrict__ lgn_mask,   // [lgn_C]
    const uint4* __restrict__ bkg_mask,   // [bkg_C]
    int R, float* __restrict__ out)
{
    int r = blockIdx.x * 256 + threadIdx.x;
    if (r >= R) return;

    float acc[T_STEPS];
    #pragma unroll
    for (int t = 0; t < T_STEPS; ++t) acc[t] = 0.0f;

    // conditional accumulate of one 32-bit mask word into acc[base..base+31]
    #define ACC_WORD(mw, base)                                              \
        _Pragma("unroll")                                                   \
        for (int t = 0; t < 32; ++t) {                                      \
            int sel = ((int)((mw) << (31 - t))) >> 31;  /* bfe_i32 */       \
            acc[(base) + t] += __int_as_float(sel & wbits);                 \
        }

    // LGN contributions
    {
        int i0 = lgn_start[r], i1 = lgn_start[r + 1];
        for (int i = i0; i < i1; ++i) {
            float wv = lgn_w[i];
            int wbits = __float_as_int(wv);
            uint4 m = lgn_mask[lgn_cols[i]];
            ACC_WORD(m.x, 0)
            ACC_WORD(m.y, 32)
            ACC_WORD(m.z, 64)
            ACC_WORD(m.w, 96)
        }
    }
    // BKG contributions
    {
        int i0 = bkg_start[r], i1 = bkg_start[r + 1];
        for (int i = i0; i < i1; ++i) {
            float wv = bkg_w[i];
            int wbits = __float_as_int(wv);
            uint4 m = bkg_mask[bkg_cols[i]];
            ACC_WORD(m.x, 0)
            ACC_WORD(m.y, 32)
            ACC_WORD(m.z, 64)
            ACC_WORD(m.w, 96)
        }
    }
    #undef ACC_WORD

    float* op = out + r;
    #pragma unroll
    for (int t = 0; t < T_STEPS; ++t) op[(size_t)t * R] = acc[t];
}

// ---------------------------------------------------------------------------
// Fallback (small ws): inline binary search + direct float gathers.
// ---------------------------------------------------------------------------
__global__ __launch_bounds__(256) void sparse_fallback_kernel(
    const int* __restrict__ lgn_rows, const int* __restrict__ lgn_cols,
    const float* __restrict__ lgn_w, int nnz_l,
    const int* __restrict__ bkg_rows, const int* __restrict__ bkg_cols,
    const float* __restrict__ bkg_w, int nnz_b,
    const float* __restrict__ lgn_spikes, const float* __restrict__ bkg_spikes,
    int lgn_C, int bkg_C, int R,
    float* __restrict__ out)
{
    int r = blockIdx.x * 256 + threadIdx.x;
    int q = blockIdx.y;
    if (r >= R) return;

    float acc[32];
    #pragma unroll
    for (int t = 0; t < 32; ++t) acc[t] = 0.0f;

    {
        int lo = 0, hi = nnz_l;
        while (lo < hi) { int mid = (lo + hi) >> 1; if (lgn_rows[mid] < r) lo = mid + 1; else hi = mid; }
        for (int i = lo; i < nnz_l && lgn_rows[i] == r; ++i) {
            float wt = lgn_w[i];
            const float* sp = lgn_spikes + (size_t)(q * 32) * lgn_C + lgn_cols[i];
            #pragma unroll
            for (int t = 0; t < 32; ++t)
                acc[t] = fmaf(wt, sp[(size_t)t * lgn_C], acc[t]);
        }
    }
    {
        int lo = 0, hi = nnz_b;
        while (lo < hi) { int mid = (lo + hi) >> 1; if (bkg_rows[mid] < r) lo = mid + 1; else hi = mid; }
        for (int i = lo; i < nnz_b && bkg_rows[i] == r; ++i) {
            float wt = bkg_w[i];
            const float* sp = bkg_spikes + (size_t)(q * 32) * bkg_C + bkg_cols[i];
            #pragma unroll
            for (int t = 0; t < 32; ++t)
                acc[t] = fmaf(wt, sp[(size_t)t * bkg_C], acc[t]);
        }
    }

    float* op = out + (size_t)(q * 32) * R + r;
    #pragma unroll
    for (int t = 0; t < 32; ++t) op[(size_t)t * R] = acc[t];
}

extern "C" void kernel_launch(void* const* d_in, const int* in_sizes, int n_in,
                              void* d_out, int out_size, void* d_ws, size_t ws_size,
                              hipStream_t stream)
{
    const float* lgn_spikes = (const float*)d_in[0];
    const float* bkg_spikes = (const float*)d_in[1];
    const int*   lgn_rows   = (const int*)d_in[2];
    const int*   lgn_cols   = (const int*)d_in[3];
    const float* lgn_w      = (const float*)d_in[4];
    const int*   bkg_rows   = (const int*)d_in[5];
    const int*   bkg_cols   = (const int*)d_in[6];
    const float* bkg_w      = (const float*)d_in[7];
    float* out = (float*)d_out;

    const int nnz_l = in_sizes[2];
    const int nnz_b = in_sizes[5];
    const int lgn_C = in_sizes[0] / T_STEPS;   // 17400
    const int bkg_C = in_sizes[1] / T_STEPS;   // 100
    const int R     = out_size / T_STEPS;      // 200000

    // ws layout (16B-aligned sections)
    size_t off = 0;
    auto take = [&](size_t bytes) { size_t o = off; off = (off + bytes + 15) & ~(size_t)15; return o; };
    size_t o_lgn_start = take((size_t)(R + 1) * sizeof(int));
    size_t o_bkg_start = take((size_t)(R + 1) * sizeof(int));
    size_t o_lgn_mask  = take((size_t)lgn_C * sizeof(uint4));
    size_t o_bkg_mask  = take((size_t)bkg_C * sizeof(uint4));
    size_t need = off;

    dim3 blk(256);

    if (ws_size >= need) {
        char* ws = (char*)d_ws;
        int* lgn_start = (int*)(ws + o_lgn_start);
        int* bkg_start = (int*)(ws + o_bkg_start);
        uint4* lgn_mask = (uint4*)(ws + o_lgn_mask);
        uint4* bkg_mask = (uint4*)(ws + o_bkg_mask);

        dim3 grid_ptr((R + 1 + 255) / 256, 2);
        build_row_ptr2_kernel<<<grid_ptr, blk, 0, stream>>>(
            lgn_rows, nnz_l, lgn_start, bkg_rows, nnz_b, bkg_start, R);

        int totC = lgn_C + bkg_C;
        build_masks2_kernel<<<(totC + 255) / 256, blk, 0, stream>>>(
            lgn_spikes, lgn_C, lgn_mask, bkg_spikes, bkg_C, bkg_mask);

        sparse_main_kernel<<<(R + 255) / 256, blk, 0, stream>>>(
            lgn_cols, lgn_w, lgn_start,
            bkg_cols, bkg_w, bkg_start,
            lgn_mask, bkg_mask,
            R, out);
    } else {
        dim3 grid_main((R + 255) / 256, 4);
        sparse_fallback_kernel<<<grid_main, blk, 0, stream>>>(
            lgn_rows, lgn_cols, lgn_w, nnz_l,
            bkg_rows, bkg_cols, bkg_w, nnz_b,
            lgn_spikes, bkg_spikes,
            lgn_C, bkg_C, R, out);
    }
}